// Round 9
// baseline (268.366 us; speedup 1.0000x reference)
//
#include <hip/hip_runtime.h>
#include <stdint.h>

#define DIM   768
#define NHEAD 12
#define HD    64
#define BATCH 8
#define SEQ   1024
#define MROWS (BATCH * SEQ)   // 8192
#define EPSLN 1e-5f
#define SM_M  10.0f           // fixed softmax shift; |s| <= 8 hard after LN + 1/8 scale

typedef __attribute__((ext_vector_type(8))) short s8v;   // 8 bf16 = MFMA A/B frag
typedef __attribute__((ext_vector_type(4))) short s4v;
typedef __attribute__((ext_vector_type(4))) float f32x4;

__device__ inline short f2bf(float f) {
    union { float f; unsigned u; } v; v.f = f;
    unsigned r = v.u + 0x7FFFu + ((v.u >> 16) & 1u);   // RNE
    return (short)(r >> 16);
}
__device__ inline float bf2f(short s) {
    union { unsigned u; float f; } v;
    v.u = ((unsigned)(unsigned short)s) << 16;
    return v.f;
}
// pack two fp32 -> two bf16 in one u32 via v_perm (round-half-up)
__device__ inline unsigned pk2bf(float lo, float hi) {
    union { float f; unsigned u; } a, b; a.f = lo; b.f = hi;
    return __builtin_amdgcn_perm(b.u + 0x8000u, a.u + 0x8000u, 0x07060302u);
}
// async global->LDS, 16 B per lane (LDS dst is wave-uniform base + lane*16)
__device__ inline void gload16(const void* g, void* l) {
    __builtin_amdgcn_global_load_lds(
        (const __attribute__((address_space(1))) void*)g,
        (__attribute__((address_space(3))) void*)l, 16, 0, 0);
}
// raw barrier + fine-grained vmcnt: the compiler's __syncthreads emits a full
// vmcnt(0) drain, killing async prefetch. Raw s_barrier (m139) + explicit
// s_waitcnt vmcnt(N) waits only the OLDEST (outstanding-N) loads (m135).
#define WAITVM(N) asm volatile("s_waitcnt vmcnt(" #N ")" ::: "memory")
#define HARDBAR() asm volatile("s_barrier" ::: "memory")

// ---------------------------------------------------------------------------
// single fp32 -> bf16 conversion pass over x | qkv_w | proj_w (float4 units)
// ---------------------------------------------------------------------------
#define N4_X (MROWS * DIM / 4)          // 1572864
#define N4_W1 (3 * DIM * DIM / 4)       // 442368
#define N4_W2 (DIM * DIM / 4)           // 147456
__global__ __launch_bounds__(256) void cvt_all(
    const float* __restrict__ x, const float* __restrict__ w1,
    const float* __restrict__ w2, short* __restrict__ dx,
    short* __restrict__ dw1, short* __restrict__ dw2)
{
    size_t i = (size_t)blockIdx.x * 256 + threadIdx.x;
    const float* s; short* d;
    if (i < N4_X)                { s = x  + i * 4;               d = dx  + i * 4; }
    else if (i < N4_X + N4_W1)   { size_t j = i - N4_X;          s = w1 + j * 4; d = dw1 + j * 4; }
    else                         { size_t j = i - N4_X - N4_W1;  s = w2 + j * 4; d = dw2 + j * 4; }
    float4 v = *(const float4*)s;
    uint2 o; o.x = pk2bf(v.x, v.y); o.y = pk2bf(v.z, v.w);
    *(uint2*)d = o;
}

// ---------------------------------------------------------------------------
// bf16 MFMA GEMM: C = A @ W^T + bias. A[M][768], W[N][768]. BM x 128 tile,
// 256 thr = 4 waves (2x2 of (BM/2)x64), BK=32, 16x16x32 MFMA.
// K-loop: RING-3 LDS buffers + raw s_barrier + explicit vmcnt(oldest-slab):
// prefetch distance 2 stays in flight across the barrier (never drained).
// Per-iter: waitvm(slab k landed) -> s_barrier -> issue stage k+2 -> ds_read
// slab k -> MFMA. Safety: a wave passing barrier k has consumed slab k-1
// (lgkm wait before its MFMAs), and (k+2)%3 == (k-1)%3 != k%3, (k+1)%3.
// XOR source-chunk swizzle (verified 0 conflicts r6/r7).
// qkv_mode (BM=128): scatter q,k bf16 [B,H,N,64]; v bf16 transposed.
// plain: fp32 out [M][Ncols] + bias (BM=64 for skinny proj: 768 blocks).
// ---------------------------------------------------------------------------
template<int BM>
__global__ __launch_bounds__(256) void gemm_mfma(
    const short* __restrict__ A, const short* __restrict__ W,
    const float* __restrict__ bias,
    short* __restrict__ oq, short* __restrict__ ok, short* __restrict__ ov,
    float* __restrict__ oplain, int Ncols, int qkv_mode)
{
    constexpr int MT = BM / 32;            // m-tiles per wave
    constexpr int KITERS = DIM / 32;       // 24
    __shared__ __align__(16) short As[3][BM * 32];
    __shared__ __align__(16) short Bs[3][128 * 32];

    const int tid  = threadIdx.x;
    const int m0   = blockIdx.y * BM;
    const int n0   = blockIdx.x * 128;
    const int w    = tid >> 6, lane = tid & 63;
    const int quad = lane >> 4, l16 = lane & 15;
    const int wm   = (w & 1) * (BM / 2), wn = (w >> 1) * 64;
    const int cswz = (quad ^ ((l16 >> 1) & 3)) * 8;   // swizzled frag k-offset

    auto stage = [&](int k0, int s) {
#pragma unroll
        for (int i = 0; i < BM / 64; ++i) {         // A slab (BM x 32)
            int f   = i * 256 + tid;
            int row = f >> 2;
            int c   = (f & 3) ^ ((row >> 1) & 3);
            gload16(&A[(size_t)(m0 + row) * DIM + k0 + c * 8], &As[s][f * 8]);
        }
#pragma unroll
        for (int i = 0; i < 2; ++i) {               // B slab (128 x 32)
            int f   = i * 256 + tid;
            int row = f >> 2;
            int c   = (f & 3) ^ ((row >> 1) & 3);
            gload16(&W[(size_t)(n0 + row) * DIM + k0 + c * 8], &Bs[s][f * 8]);
        }
    };

    f32x4 acc[MT][4];
#pragma unroll
    for (int i = 0; i < MT; ++i)
#pragma unroll
        for (int j = 0; j < 4; ++j) acc[i][j] = (f32x4){0.f, 0.f, 0.f, 0.f};

    stage(0, 0);
    stage(32, 1);
    for (int it = 0; it < KITERS; ++it) {
        // wait for slab `it` only (oldest); slabs it+1, it+2 remain in flight
        if (it == KITERS - 1) { WAITVM(0); }
        else if constexpr (BM == 128) { WAITVM(4); }   // 4 gload16/slab/wave
        else                          { WAITVM(3); }   // 3 gload16/slab/wave
        HARDBAR();
        if (it + 2 < KITERS) stage((it + 2) * 32, (it + 2) % 3);
        const int s = it % 3;
        s8v af[MT], bw[4];
#pragma unroll
        for (int t = 0; t < MT; ++t)
            af[t] = *(const s8v*)&As[s][(wm + t * 16 + l16) * 32 + cswz];
#pragma unroll
        for (int t = 0; t < 4; ++t)
            bw[t] = *(const s8v*)&Bs[s][(wn + t * 16 + l16) * 32 + cswz];
#pragma unroll
        for (int mt = 0; mt < MT; ++mt)
#pragma unroll
            for (int nt = 0; nt < 4; ++nt)
                acc[mt][nt] = __builtin_amdgcn_mfma_f32_16x16x32_bf16(
                    af[mt], bw[nt], acc[mt][nt], 0, 0, 0);
    }

    // C layout per 16x16 tile: row m = quad*4 + i, col n = l16
    if (qkv_mode) {
        const int which = n0 / DIM;        // 0=q, 1=k, 2=v (128-tiles never cross)
#pragma unroll
        for (int mt = 0; mt < MT; ++mt)
#pragma unroll
            for (int nt = 0; nt < 4; ++nt)
#pragma unroll
                for (int i = 0; i < 4; ++i) {
                    int m  = m0 + wm + mt * 16 + quad * 4 + i;
                    int n  = n0 + wn + nt * 16 + l16;
                    float cv = acc[mt][nt][i] + bias[n];
                    int bb = m >> 10, nn = m & 1023;
                    int d  = n - which * DIM;
                    int hh = d >> 6, e = d & 63;
                    if (which == 2)
                        ov[(((size_t)(bb * NHEAD + hh)) * HD + e) * SEQ + nn] = f2bf(cv);
                    else {
                        short* dst = which ? ok : oq;
                        dst[(((size_t)(bb * NHEAD + hh)) * SEQ + nn) * HD + e] = f2bf(cv);
                    }
                }
    } else {
#pragma unroll
        for (int mt = 0; mt < MT; ++mt)
#pragma unroll
            for (int nt = 0; nt < 4; ++nt)
#pragma unroll
                for (int i = 0; i < 4; ++i) {
                    int m = m0 + wm + mt * 16 + quad * 4 + i;
                    int n = n0 + wn + nt * 16 + l16;
                    oplain[(size_t)m * Ncols + n] = acc[mt][nt][i] + bias[n];
                }
    }
}

// ---------------------------------------------------------------------------
// LayerNorm(hd=64) on bf16 in-place; q rows (first half) folded by 1/8.
// ---------------------------------------------------------------------------
__global__ __launch_bounds__(256) void ln64b(
    short* __restrict__ p, const float* __restrict__ gamma,
    const float* __restrict__ beta)
{
    const int row  = blockIdx.x * 4 + (threadIdx.x >> 6);
    const int lane = threadIdx.x & 63;
    short* r = p + (size_t)row * 64;
    float v = bf2f(r[lane]);
    float s = v;
#pragma unroll
    for (int m = 1; m < 64; m <<= 1) s += __shfl_xor(s, m);
    float mu = s * (1.f / 64.f);
    float d  = v - mu;
    float s2 = d * d;
#pragma unroll
    for (int m = 1; m < 64; m <<= 1) s2 += __shfl_xor(s2, m);
    float var  = s2 * (1.f / 64.f);
    float outv = d * rsqrtf(var + EPSLN) * gamma[lane] + beta[lane];
    if (row < BATCH * NHEAD * SEQ) outv *= 0.125f;   // q rows: fold softmax scale
    r[lane] = f2bf(outv);
}

// ---------------------------------------------------------------------------
// MFMA flash attention, key-split waves, S^T formulation (unchanged from r8).
// ---------------------------------------------------------------------------
__global__ __launch_bounds__(256) void attn_mfma(
    const short* __restrict__ q, const short* __restrict__ k,
    const short* __restrict__ vt, short* __restrict__ O)
{
    const int bh   = blockIdx.y;
    const int b    = bh / NHEAD;
    const int h    = bh % NHEAD;
    const int q0   = blockIdx.x * 64;
    const int tid  = threadIdx.x;
    const int w    = tid >> 6;
    const int lane = tid & 63;
    const int quad = lane >> 4;
    const int l16  = lane & 15;

    __shared__ __align__(16) char smem[20480];   // P (main loop) / Obuf (epilogue)
    __shared__ float denom[4][64];

    short (*Pw)[40]   = (short(*)[40])(smem + (size_t)w * (64 * 40 * 2));
    float (*Obuf)[68] = (float(*)[68])smem;      // [64 q][64 e + pad]

    const size_t base   = (size_t)bh * SEQ * HD;
    const size_t vtbase = (size_t)bh * HD * SEQ;

    // hoist Q B-frags: B[k=d][n=q]: lane -> q = qt*16+l16, d = hf*32+quad*8+jj
    s8v qB[4][2];
#pragma unroll
    for (int qt = 0; qt < 4; ++qt)
#pragma unroll
        for (int hf = 0; hf < 2; ++hf)
            qB[qt][hf] = *(const s8v*)&q[base + (size_t)(q0 + qt * 16 + l16) * HD
                                         + hf * 32 + quad * 8];

    f32x4 oacc[4][4];                 // [et][qt] : O^T partials
    float lacc[4] = {0.f, 0.f, 0.f, 0.f};
#pragma unroll
    for (int a = 0; a < 4; ++a)
#pragma unroll
        for (int c = 0; c < 4; ++c) oacc[a][c] = (f32x4){0.f, 0.f, 0.f, 0.f};

#pragma unroll 2
    for (int jb = 0; jb < 8; ++jb) {
        const int kb = jb * 128 + w * 32;    // this wave's 32-key window

        // K A-frags: A[m=key][k=d]: lane -> key = kt*16+l16, d = hf*32+quad*8+jj
        s8v kA[2][2];
#pragma unroll
        for (int kt = 0; kt < 2; ++kt)
#pragma unroll
            for (int hf = 0; hf < 2; ++hf)
                kA[kt][hf] = *(const s8v*)&k[base + (size_t)(kb + kt * 16 + l16) * HD
                                             + hf * 32 + quad * 8];
        // V^T A-frags: A[m=e][k=key]: lane -> e = et*16+l16, key = quad*8+jj
        s8v va[4];
#pragma unroll
        for (int et = 0; et < 4; ++et)
            va[et] = *(const s8v*)&vt[vtbase + (size_t)(et * 16 + l16) * SEQ
                                      + kb + quad * 8];

        // ---- S^T = K Q^T, exp, packed P[q][key] -> LDS ----
#pragma unroll
        for (int qt = 0; qt < 4; ++qt)
#pragma unroll
            for (int kt = 0; kt < 2; ++kt) {
                f32x4 c = (f32x4){0.f, 0.f, 0.f, 0.f};
                c = __builtin_amdgcn_mfma_f32_16x16x32_bf16(kA[kt][0], qB[qt][0], c, 0, 0, 0);
                c = __builtin_amdgcn_mfma_f32_16x16x32_bf16(kA[kt][1], qB[qt][1], c, 0, 0, 0);
                // C: (key = kt*16 + quad*4 + i, q = qt*16 + l16)
                float p0 = __expf(c[0] - SM_M), p1 = __expf(c[1] - SM_M);
                float p2 = __expf(c[2] - SM_M), p3 = __expf(c[3] - SM_M);
                lacc[qt] += (p0 + p1) + (p2 + p3);
                uint2 pk; pk.x = pk2bf(p0, p1); pk.y = pk2bf(p2, p3);
                *(uint2*)&Pw[qt * 16 + l16][kt * 16 + quad * 4] = pk;   // b64
            }

        // ---- P^T B-frags: B[k=key][n=q] = Pw[q][key], contiguous b128 ----
        s8v pb[4];
#pragma unroll
        for (int qt = 0; qt < 4; ++qt)
            pb[qt] = *(const s8v*)&Pw[qt * 16 + l16][quad * 8];

        // ---- O^T += V^T P^T (K = 32: one MFMA per tile) ----
#pragma unroll
        for (int et = 0; et < 4; ++et)
#pragma unroll
            for (int qt = 0; qt < 4; ++qt)
                oacc[et][qt] = __builtin_amdgcn_mfma_f32_16x16x32_bf16(
                    va[et], pb[qt], oacc[et][qt], 0, 0, 0);
    }

    // ---- denominator: lane holds col q = qt*16+l16; sum across quads ----
#pragma unroll
    for (int qt = 0; qt < 4; ++qt) {
        float s = lacc[qt];
        s += __shfl_xor(s, 16);
        s += __shfl_xor(s, 32);
        denom[w][qt * 16 + l16] = s;     // 4 quads write same value: benign
    }
    __syncthreads();                     // main loop done; P region now dead

    // ---- cross-wave O sum into Obuf (float4: e = et*16+quad*4 .. +3) ----
    for (int r = 0; r < 4; ++r) {
        if (w == r) {
#pragma unroll
            for (int et = 0; et < 4; ++et)
#pragma unroll
                for (int qt = 0; qt < 4; ++qt) {
                    float* dst = &Obuf[qt * 16 + l16][et * 16 + quad * 4];
                    float4 ov;
                    if (r == 0) ov = make_float4(0.f, 0.f, 0.f, 0.f);
                    else        ov = *(float4*)dst;
                    ov.x += oacc[et][qt][0]; ov.y += oacc[et][qt][1];
                    ov.z += oacc[et][qt][2]; ov.w += oacc[et][qt][3];
                    *(float4*)dst = ov;
                }
        }
        __syncthreads();
    }

    // ---- scale + store: thread t -> (q = t/4, e-span = (t%4)*16) ----
    const int qq = tid >> 2;
    const int e0 = (tid & 3) * 16;
    float linv = 1.0f / (denom[0][qq] + denom[1][qq] + denom[2][qq] + denom[3][qq]);
    float4 f0 = *(float4*)&Obuf[qq][e0];
    float4 f1 = *(float4*)&Obuf[qq][e0 + 4];
    float4 f2 = *(float4*)&Obuf[qq][e0 + 8];
    float4 f3 = *(float4*)&Obuf[qq][e0 + 12];
    short* op = &O[((size_t)b * SEQ + q0 + qq) * DIM + h * HD + e0];
    uint4 o1, o2;
    o1.x = pk2bf(f0.x * linv, f0.y * linv);
    o1.y = pk2bf(f0.z * linv, f0.w * linv);
    o1.z = pk2bf(f1.x * linv, f1.y * linv);
    o1.w = pk2bf(f1.z * linv, f1.w * linv);
    o2.x = pk2bf(f2.x * linv, f2.y * linv);
    o2.y = pk2bf(f2.z * linv, f2.w * linv);
    o2.z = pk2bf(f3.x * linv, f3.y * linv);
    o2.w = pk2bf(f3.z * linv, f3.w * linv);
    *(uint4*)&op[0] = o1;
    *(uint4*)&op[8] = o2;
}

// ---------------------------------------------------------------------------
extern "C" void kernel_launch(void* const* d_in, const int* in_sizes, int n_in,
                              void* d_out, int out_size, void* d_ws, size_t ws_size,
                              hipStream_t stream)
{
    const float* x      = (const float*)d_in[0];
    const float* qkv_w  = (const float*)d_in[1];
    const float* qkv_b  = (const float*)d_in[2];
    const float* proj_w = (const float*)d_in[3];
    const float* proj_b = (const float*)d_in[4];
    const float* gamma  = (const float*)d_in[5];
    const float* beta   = (const float*)d_in[6];
    float* out = (float*)d_out;

    const size_t PER = (size_t)BATCH * NHEAD * SEQ * HD;  // 6291456
    short* qb  = (short*)d_ws;                 // bf16 q   [B,H,N,64]
    short* kb  = qb + PER;                     // bf16 k   [B,H,N,64]
    short* vtb = kb + PER;                     // bf16 v^T [B,H,64,N]
    short* ob  = vtb + PER;                    // bf16 o   [B,N,768]
    short* xb  = ob + PER;                     // bf16 x   [8192,768]
    short* wqb = xb + (size_t)MROWS * DIM;     // bf16 qkv_w [2304,768]
    short* wpb = wqb + (size_t)3 * DIM * DIM;  // bf16 proj_w [768,768]

    // 0) one fused fp32 -> bf16 conversion pass
    cvt_all<<<dim3((N4_X + N4_W1 + N4_W2) / 256), 256, 0, stream>>>(
        x, qkv_w, proj_w, xb, wqb, wpb);

    // 1) qkv GEMM -> q,k bf16 [B,H,N,64]; v bf16 transposed [B,H,64,N]
    gemm_mfma<128><<<dim3(2304 / 128, MROWS / 128), 256, 0, stream>>>(
        xb, wqb, qkv_b, qb, kb, vtb, nullptr, 2304, 1);

    // 2) LayerNorm(64) on q,k (q folded by 1/8)
    ln64b<<<dim3(2 * PER / 64 / 4), 256, 0, stream>>>(qb, gamma, beta);

    // 3) MFMA flash attention (key-split, S^T) -> o bf16 [B,N,768]
    attn_mfma<<<dim3(SEQ / 64, BATCH * NHEAD), 256, 0, stream>>>(qb, kb, vtb, ob);

    // 4) out = o @ proj_w^T + proj_b (fp32 out), 64-row tiles: 768 blocks
    gemm_mfma<64><<<dim3(DIM / 128, MROWS / 64), 256, 0, stream>>>(
        ob, wpb, proj_b, nullptr, nullptr, nullptr, out, DIM, 0);
}

// Round 10
// 251.780 us; speedup vs baseline: 1.0659x; 1.0659x over previous
//
#include <hip/hip_runtime.h>
#include <stdint.h>

#define DIM   768
#define NHEAD 12
#define HD    64
#define BATCH 8
#define SEQ   1024
#define MROWS (BATCH * SEQ)   // 8192
#define EPSLN 1e-5f
#define SM_M  10.0f           // fixed softmax shift; |s| <= 8 hard after LN + 1/8 scale

typedef __attribute__((ext_vector_type(8))) short s8v;   // 8 bf16 = MFMA A/B frag
typedef __attribute__((ext_vector_type(4))) short s4v;
typedef __attribute__((ext_vector_type(4))) float f32x4;

__device__ inline short f2bf(float f) {
    union { float f; unsigned u; } v; v.f = f;
    unsigned r = v.u + 0x7FFFu + ((v.u >> 16) & 1u);   // RNE
    return (short)(r >> 16);
}
__device__ inline float bf2f(short s) {
    union { unsigned u; float f; } v;
    v.u = ((unsigned)(unsigned short)s) << 16;
    return v.f;
}
// pack two fp32 -> two bf16 in one u32 via v_perm (round-half-up)
__device__ inline unsigned pk2bf(float lo, float hi) {
    union { float f; unsigned u; } a, b; a.f = lo; b.f = hi;
    return __builtin_amdgcn_perm(b.u + 0x8000u, a.u + 0x8000u, 0x07060302u);
}
// async global->LDS, 16 B per lane (LDS dst is wave-uniform base + lane*16)
__device__ inline void gload16(const void* g, void* l) {
    __builtin_amdgcn_global_load_lds(
        (const __attribute__((address_space(1))) void*)g,
        (__attribute__((address_space(3))) void*)l, 16, 0, 0);
}

// ---------------------------------------------------------------------------
// single fp32 -> bf16 conversion pass over x | qkv_w | proj_w (float4 units)
// ---------------------------------------------------------------------------
#define N4_X (MROWS * DIM / 4)          // 1572864
#define N4_W1 (3 * DIM * DIM / 4)       // 442368
#define N4_W2 (DIM * DIM / 4)           // 147456
__global__ __launch_bounds__(256) void cvt_all(
    const float* __restrict__ x, const float* __restrict__ w1,
    const float* __restrict__ w2, short* __restrict__ dx,
    short* __restrict__ dw1, short* __restrict__ dw2)
{
    size_t i = (size_t)blockIdx.x * 256 + threadIdx.x;
    const float* s; short* d;
    if (i < N4_X)                { s = x  + i * 4;               d = dx  + i * 4; }
    else if (i < N4_X + N4_W1)   { size_t j = i - N4_X;          s = w1 + j * 4; d = dw1 + j * 4; }
    else                         { size_t j = i - N4_X - N4_W1;  s = w2 + j * 4; d = dw2 + j * 4; }
    float4 v = *(const float4*)s;
    uint2 o; o.x = pk2bf(v.x, v.y); o.y = pk2bf(v.z, v.w);
    *(uint2*)d = o;
}

// ---------------------------------------------------------------------------
// bf16 MFMA GEMM (r8 structure — measured best): C = A @ W^T + bias.
// BM x 128 tile, 256 thr = 4 waves (2x2), BK=64, 16x16x32 MFMA in 2 ks-halves,
// single-buffer LDS + gload16 + 2 barriers/iter, XOR chunk swizzle (0 confl).
// qkv_mode (BM=128): scatter RAW q,k bf16 [B,H,N,64] (LN fused in attn);
//                    v bf16 transposed [B,H,64,N].
// plain: fp32 out [M][Ncols] + bias (BM=64 for skinny proj: 768 blocks).
// ---------------------------------------------------------------------------
template<int BM>
__global__ __launch_bounds__(256) void gemm_mfma(
    const short* __restrict__ A, const short* __restrict__ W,
    const float* __restrict__ bias,
    short* __restrict__ oq, short* __restrict__ ok, short* __restrict__ ov,
    float* __restrict__ oplain, int Ncols, int qkv_mode)
{
    constexpr int MT = BM / 32;            // m-tiles per wave
    __shared__ __align__(16) short As[BM * 64];
    __shared__ __align__(16) short Bs[128 * 64];

    const int tid  = threadIdx.x;
    const int m0   = blockIdx.y * BM;
    const int n0   = blockIdx.x * 128;
    const int w    = tid >> 6, lane = tid & 63;
    const int quad = lane >> 4, l16 = lane & 15;
    const int wm   = (w & 1) * (BM / 2), wn = (w >> 1) * 64;
    const int rsw  = l16 & 7;              // read-row swizzle key

    f32x4 acc[MT][4];
#pragma unroll
    for (int i = 0; i < MT; ++i)
#pragma unroll
        for (int j = 0; j < 4; ++j) acc[i][j] = (f32x4){0.f, 0.f, 0.f, 0.f};

    for (int k0 = 0; k0 < DIM; k0 += 64) {
#pragma unroll
        for (int i = 0; i < BM / 32; ++i) {         // stage A slab (BM x 64)
            int f   = i * 256 + tid;
            int row = f >> 3;
            int c   = (f & 7) ^ (row & 7);
            gload16(&A[(size_t)(m0 + row) * DIM + k0 + c * 8], &As[f * 8]);
        }
#pragma unroll
        for (int i = 0; i < 4; ++i) {               // stage B slab (128 x 64)
            int f   = i * 256 + tid;
            int row = f >> 3;
            int c   = (f & 7) ^ (row & 7);
            gload16(&W[(size_t)(n0 + row) * DIM + k0 + c * 8], &Bs[f * 8]);
        }
        __syncthreads();                 // drain gload16 + all waves arrived
#pragma unroll
        for (int ks = 0; ks < 2; ++ks) {
            const int ch = ((ks * 4 + quad) ^ rsw) * 8;
            s8v af[MT], bw[4];
#pragma unroll
            for (int t = 0; t < MT; ++t)
                af[t] = *(const s8v*)&As[(wm + t * 16 + l16) * 64 + ch];
#pragma unroll
            for (int t = 0; t < 4; ++t)
                bw[t] = *(const s8v*)&Bs[(wn + t * 16 + l16) * 64 + ch];
#pragma unroll
            for (int mt = 0; mt < MT; ++mt)
#pragma unroll
                for (int nt = 0; nt < 4; ++nt)
                    acc[mt][nt] = __builtin_amdgcn_mfma_f32_16x16x32_bf16(
                        af[mt], bw[nt], acc[mt][nt], 0, 0, 0);
        }
        __syncthreads();                 // frags consumed; next stage may overwrite
    }

    // C layout per 16x16 tile: row m = quad*4 + i, col n = l16
    if (qkv_mode) {
        const int which = n0 / DIM;        // 0=q, 1=k, 2=v (128-tiles never cross)
#pragma unroll
        for (int mt = 0; mt < MT; ++mt)
#pragma unroll
            for (int nt = 0; nt < 4; ++nt)
#pragma unroll
                for (int i = 0; i < 4; ++i) {
                    int m  = m0 + wm + mt * 16 + quad * 4 + i;
                    int n  = n0 + wn + nt * 16 + l16;
                    float cv = acc[mt][nt][i] + bias[n];
                    int bb = m >> 10, nn = m & 1023;
                    int d  = n - which * DIM;
                    int hh = d >> 6, e = d & 63;
                    if (which == 2)
                        ov[(((size_t)(bb * NHEAD + hh)) * HD + e) * SEQ + nn] = f2bf(cv);
                    else {
                        short* dst = which ? ok : oq;
                        dst[(((size_t)(bb * NHEAD + hh)) * SEQ + nn) * HD + e] = f2bf(cv);
                    }
                }
    } else {
#pragma unroll
        for (int mt = 0; mt < MT; ++mt)
#pragma unroll
            for (int nt = 0; nt < 4; ++nt)
#pragma unroll
                for (int i = 0; i < 4; ++i) {
                    int m = m0 + wm + mt * 16 + quad * 4 + i;
                    int n = n0 + wn + nt * 16 + l16;
                    oplain[(size_t)m * Ncols + n] = acc[mt][nt][i] + bias[n];
                }
    }
}

// ---------------------------------------------------------------------------
// MFMA flash attention with FUSED LayerNorm(64) on q,k.
// Key-split waves, S^T formulation (r8 structure). In both the Q B-frag and
// K A-frag layouts, one q/k row's 64 elements live on 4 lanes (same l16,
// quad=0..3, 16 elems each): LN = in-lane sums + shfl_xor(16,32) + in-lane
// normalize + repack. Q once per block (x1/8 folded); K per jb (redundant
// across q-blocks, cheap VALU). gamma/beta preloaded bf16-packed.
// ---------------------------------------------------------------------------
__global__ __launch_bounds__(256) void attn_mfma(
    const short* __restrict__ q, const short* __restrict__ k,
    const short* __restrict__ vt, short* __restrict__ O,
    const float* __restrict__ gamma, const float* __restrict__ beta)
{
    const int bh   = blockIdx.y;
    const int b    = bh / NHEAD;
    const int h    = bh % NHEAD;
    const int q0   = blockIdx.x * 64;
    const int tid  = threadIdx.x;
    const int w    = tid >> 6;
    const int lane = tid & 63;
    const int quad = lane >> 4;
    const int l16  = lane & 15;

    __shared__ __align__(16) char smem[20480];   // P (main loop) / Obuf (epilogue)
    __shared__ float denom[4][64];

    short (*Pw)[40]   = (short(*)[40])(smem + (size_t)w * (64 * 40 * 2));
    float (*Obuf)[68] = (float(*)[68])smem;      // [64 q][64 e + pad]

    const size_t base   = (size_t)bh * SEQ * HD;
    const size_t vtbase = (size_t)bh * HD * SEQ;

    // gamma/beta for this lane's element pattern e = hf*32 + quad*8 + j,
    // packed bf16 (slot j of g0v/b0v: hf=0; g1v/b1v: hf=1)
    s8v g0v, g1v, b0v, b1v;
#pragma unroll
    for (int j = 0; j < 8; ++j) {
        g0v[j] = f2bf(gamma[quad * 8 + j]);
        g1v[j] = f2bf(gamma[32 + quad * 8 + j]);
        b0v[j] = f2bf(beta [quad * 8 + j]);
        b1v[j] = f2bf(beta [32 + quad * 8 + j]);
    }

    // LN over a frag pair (row spread across quads; reduce via xor 16,32)
    auto lnpair = [&](s8v& f0, s8v& f1, float scale) {
        float x0[8], x1[8], s = 0.f, s2 = 0.f;
#pragma unroll
        for (int j = 0; j < 8; ++j) {
            x0[j] = bf2f(f0[j]); x1[j] = bf2f(f1[j]);
            s  += x0[j] + x1[j];
            s2 += x0[j] * x0[j] + x1[j] * x1[j];
        }
        s  += __shfl_xor(s, 16);  s  += __shfl_xor(s, 32);
        s2 += __shfl_xor(s2, 16); s2 += __shfl_xor(s2, 32);
        float mu  = s * (1.f / 64.f);
        float var = s2 * (1.f / 64.f) - mu * mu;
        float rs  = rsqrtf(var + EPSLN) * scale;
        union { unsigned u[4]; s8v v; } r0, r1;
#pragma unroll
        for (int j = 0; j < 4; ++j) {
            float a0 = (x0[2*j]   - mu) * rs * bf2f(g0v[2*j])   + bf2f(b0v[2*j])   * scale;
            float a1 = (x0[2*j+1] - mu) * rs * bf2f(g0v[2*j+1]) + bf2f(b0v[2*j+1]) * scale;
            float c0 = (x1[2*j]   - mu) * rs * bf2f(g1v[2*j])   + bf2f(b1v[2*j])   * scale;
            float c1 = (x1[2*j+1] - mu) * rs * bf2f(g1v[2*j+1]) + bf2f(b1v[2*j+1]) * scale;
            r0.u[j] = pk2bf(a0, a1);
            r1.u[j] = pk2bf(c0, c1);
        }
        f0 = r0.v; f1 = r1.v;
    };

    // hoist Q B-frags (raw), then fused LN + 1/8 scale (once per block)
    s8v qB[4][2];
#pragma unroll
    for (int qt = 0; qt < 4; ++qt) {
#pragma unroll
        for (int hf = 0; hf < 2; ++hf)
            qB[qt][hf] = *(const s8v*)&q[base + (size_t)(q0 + qt * 16 + l16) * HD
                                         + hf * 32 + quad * 8];
        lnpair(qB[qt][0], qB[qt][1], 0.125f);
    }

    f32x4 oacc[4][4];                 // [et][qt] : O^T partials
    float lacc[4] = {0.f, 0.f, 0.f, 0.f};
#pragma unroll
    for (int a = 0; a < 4; ++a)
#pragma unroll
        for (int c = 0; c < 4; ++c) oacc[a][c] = (f32x4){0.f, 0.f, 0.f, 0.f};

#pragma unroll 2
    for (int jb = 0; jb < 8; ++jb) {
        const int kb = jb * 128 + w * 32;    // this wave's 32-key window

        // K A-frags (raw) + fused LN
        s8v kA[2][2];
#pragma unroll
        for (int kt = 0; kt < 2; ++kt) {
#pragma unroll
            for (int hf = 0; hf < 2; ++hf)
                kA[kt][hf] = *(const s8v*)&k[base + (size_t)(kb + kt * 16 + l16) * HD
                                             + hf * 32 + quad * 8];
            lnpair(kA[kt][0], kA[kt][1], 1.0f);
        }
        // V^T A-frags: A[m=e][k=key]: lane -> e = et*16+l16, key = quad*8+jj
        s8v va[4];
#pragma unroll
        for (int et = 0; et < 4; ++et)
            va[et] = *(const s8v*)&vt[vtbase + (size_t)(et * 16 + l16) * SEQ
                                      + kb + quad * 8];

        // ---- S^T = K Q^T, exp, packed P[q][key] -> LDS ----
#pragma unroll
        for (int qt = 0; qt < 4; ++qt)
#pragma unroll
            for (int kt = 0; kt < 2; ++kt) {
                f32x4 c = (f32x4){0.f, 0.f, 0.f, 0.f};
                c = __builtin_amdgcn_mfma_f32_16x16x32_bf16(kA[kt][0], qB[qt][0], c, 0, 0, 0);
                c = __builtin_amdgcn_mfma_f32_16x16x32_bf16(kA[kt][1], qB[qt][1], c, 0, 0, 0);
                // C: (key = kt*16 + quad*4 + i, q = qt*16 + l16)
                float p0 = __expf(c[0] - SM_M), p1 = __expf(c[1] - SM_M);
                float p2 = __expf(c[2] - SM_M), p3 = __expf(c[3] - SM_M);
                lacc[qt] += (p0 + p1) + (p2 + p3);
                uint2 pk; pk.x = pk2bf(p0, p1); pk.y = pk2bf(p2, p3);
                *(uint2*)&Pw[qt * 16 + l16][kt * 16 + quad * 4] = pk;   // b64
            }

        // ---- P^T B-frags: B[k=key][n=q] = Pw[q][key], contiguous b128 ----
        s8v pb[4];
#pragma unroll
        for (int qt = 0; qt < 4; ++qt)
            pb[qt] = *(const s8v*)&Pw[qt * 16 + l16][quad * 8];

        // ---- O^T += V^T P^T (K = 32: one MFMA per tile) ----
#pragma unroll
        for (int et = 0; et < 4; ++et)
#pragma unroll
            for (int qt = 0; qt < 4; ++qt)
                oacc[et][qt] = __builtin_amdgcn_mfma_f32_16x16x32_bf16(
                    va[et], pb[qt], oacc[et][qt], 0, 0, 0);
    }

    // ---- denominator: lane holds col q = qt*16+l16; sum across quads ----
#pragma unroll
    for (int qt = 0; qt < 4; ++qt) {
        float s = lacc[qt];
        s += __shfl_xor(s, 16);
        s += __shfl_xor(s, 32);
        denom[w][qt * 16 + l16] = s;     // 4 quads write same value: benign
    }
    __syncthreads();                     // main loop done; P region now dead

    // ---- cross-wave O sum into Obuf (float4: e = et*16+quad*4 .. +3) ----
    for (int r = 0; r < 4; ++r) {
        if (w == r) {
#pragma unroll
            for (int et = 0; et < 4; ++et)
#pragma unroll
                for (int qt = 0; qt < 4; ++qt) {
                    float* dst = &Obuf[qt * 16 + l16][et * 16 + quad * 4];
                    float4 ov;
                    if (r == 0) ov = make_float4(0.f, 0.f, 0.f, 0.f);
                    else        ov = *(float4*)dst;
                    ov.x += oacc[et][qt][0]; ov.y += oacc[et][qt][1];
                    ov.z += oacc[et][qt][2]; ov.w += oacc[et][qt][3];
                    *(float4*)dst = ov;
                }
        }
        __syncthreads();
    }

    // ---- scale + store: thread t -> (q = t/4, e-span = (t%4)*16) ----
    const int qq = tid >> 2;
    const int e0 = (tid & 3) * 16;
    float linv = 1.0f / (denom[0][qq] + denom[1][qq] + denom[2][qq] + denom[3][qq]);
    float4 f0 = *(float4*)&Obuf[qq][e0];
    float4 f1 = *(float4*)&Obuf[qq][e0 + 4];
    float4 f2 = *(float4*)&Obuf[qq][e0 + 8];
    float4 f3 = *(float4*)&Obuf[qq][e0 + 12];
    short* op = &O[((size_t)b * SEQ + q0 + qq) * DIM + h * HD + e0];
    uint4 o1, o2;
    o1.x = pk2bf(f0.x * linv, f0.y * linv);
    o1.y = pk2bf(f0.z * linv, f0.w * linv);
    o1.z = pk2bf(f1.x * linv, f1.y * linv);
    o1.w = pk2bf(f1.z * linv, f1.w * linv);
    o2.x = pk2bf(f2.x * linv, f2.y * linv);
    o2.y = pk2bf(f2.z * linv, f2.w * linv);
    o2.z = pk2bf(f3.x * linv, f3.y * linv);
    o2.w = pk2bf(f3.z * linv, f3.w * linv);
    *(uint4*)&op[0] = o1;
    *(uint4*)&op[8] = o2;
}

// ---------------------------------------------------------------------------
extern "C" void kernel_launch(void* const* d_in, const int* in_sizes, int n_in,
                              void* d_out, int out_size, void* d_ws, size_t ws_size,
                              hipStream_t stream)
{
    const float* x      = (const float*)d_in[0];
    const float* qkv_w  = (const float*)d_in[1];
    const float* qkv_b  = (const float*)d_in[2];
    const float* proj_w = (const float*)d_in[3];
    const float* proj_b = (const float*)d_in[4];
    const float* gamma  = (const float*)d_in[5];
    const float* beta   = (const float*)d_in[6];
    float* out = (float*)d_out;

    const size_t PER = (size_t)BATCH * NHEAD * SEQ * HD;  // 6291456
    short* qb  = (short*)d_ws;                 // bf16 q   [B,H,N,64] (raw)
    short* kb  = qb + PER;                     // bf16 k   [B,H,N,64] (raw)
    short* vtb = kb + PER;                     // bf16 v^T [B,H,64,N]
    short* ob  = vtb + PER;                    // bf16 o   [B,N,768]
    short* xb  = ob + PER;                     // bf16 x   [8192,768]
    short* wqb = xb + (size_t)MROWS * DIM;     // bf16 qkv_w [2304,768]
    short* wpb = wqb + (size_t)3 * DIM * DIM;  // bf16 proj_w [768,768]

    // 0) one fused fp32 -> bf16 conversion pass
    cvt_all<<<dim3((N4_X + N4_W1 + N4_W2) / 256), 256, 0, stream>>>(
        x, qkv_w, proj_w, xb, wqb, wpb);

    // 1) qkv GEMM -> raw q,k bf16 [B,H,N,64]; v bf16 transposed [B,H,64,N]
    gemm_mfma<128><<<dim3(2304 / 128, MROWS / 128), 256, 0, stream>>>(
        xb, wqb, qkv_b, qb, kb, vtb, nullptr, 2304, 1);

    // 2) MFMA flash attention with fused LN -> o bf16 [B,N,768]
    attn_mfma<<<dim3(SEQ / 64, BATCH * NHEAD), 256, 0, stream>>>(
        qb, kb, vtb, ob, gamma, beta);

    // 3) out = o @ proj_w^T + proj_b (fp32 out), 64-row tiles: 768 blocks
    gemm_mfma<64><<<dim3(DIM / 128, MROWS / 64), 256, 0, stream>>>(
        ob, wpb, proj_b, nullptr, nullptr, nullptr, out, DIM, 0);
}